// Round 10
// baseline (213.984 us; speedup 1.0000x reference)
//
#include <hip/hip_runtime.h>
#include <hip/hip_bf16.h>

typedef __attribute__((ext_vector_type(8))) short   bf16x8;
typedef __attribute__((ext_vector_type(4))) float   f32x4;
typedef unsigned short u16;

#define NTOK 64
#define CEMB 192
#define NH   6
#define ROWB 384   // row bytes for [64][192] bf16 tiles
#define VROWB 128  // row bytes for vhT [192][64] bf16

__device__ __forceinline__ u16 f2b(float f) {
  unsigned u = __float_as_uint(f);
  unsigned r = (u + 0x7fffu + ((u >> 16) & 1u)) >> 16;  // RNE
  return (u16)r;
}

__device__ __forceinline__ unsigned cvtpk(float lo, float hi) {
  unsigned r;
  asm("v_cvt_pk_bf16_f32 %0, %1, %2" : "=v"(r) : "v"(lo), "v"(hi));
  return r;
}

__device__ __forceinline__ int swz(int row, int colbyte) {
  return colbyte ^ ((((row >> 3) ^ row) & 7) << 4);
}

// ---------------- prep: pack W^T (bf16) + gather rel_bias ----------------
__global__ void prep_kernel(const float* __restrict__ Wq, const float* __restrict__ Wk,
                            const float* __restrict__ Wv, const float* __restrict__ Wp,
                            const float* __restrict__ btab, const int* __restrict__ ridx,
                            u16* __restrict__ WT, float* __restrict__ rb) {
  int idx = blockIdx.x * 256 + threadIdx.x;
  if (idx < 4 * 36864) {
    int m = idx / 36864;
    int e = idx - m * 36864;
    int n = e / CEMB;
    int k = e - n * CEMB;
    const float* W = (m == 0) ? Wq : (m == 1) ? Wk : (m == 2) ? Wv : Wp;
    WT[idx] = f2b(W[k * CEMB + n]);          // WT[m][n][k] = W[k][n]
  } else {
    int i2 = idx - 4 * 36864;
    if (i2 < NH * 4096) {
      int h = i2 >> 12;
      int ij = i2 & 4095;
      rb[i2] = btab[ridx[ij] * NH + h];      // rb[h][i][j]
    }
  }
}

// ---------------- fused window attention (R8 base + swapped-S softmax) ----------------
__global__ __launch_bounds__(512, 4)
void wattn_kernel(const float* __restrict__ qg, const float* __restrict__ kg,
                  const float* __restrict__ vg, const float* __restrict__ maskg,
                  const float* __restrict__ bq, const float* __restrict__ bk,
                  const float* __restrict__ bv, const float* __restrict__ bp,
                  const u16* __restrict__ WT, const float* __restrict__ rb,
                  float* __restrict__ xout, float* __restrict__ attn_out) {
  __shared__ __align__(16) char smem[81920];
  char* sQ = smem;                 // raw q -> qh -> X (in-place)
  char* sK = smem + 24576;         // raw k -> kh
  char* sV = smem + 49152;         // raw v -> vhT [192][64]
  const int tid  = threadIdx.x;
  const int wave = tid >> 6;
  const int lane = tid & 63;
  const int l15  = lane & 15;
  const int lhi  = lane >> 4;
  char* sP = smem + 73728 + wave * 1024;   // per-wave P scratch (R8 layout)
  const int b = blockIdx.x;
  const float scale = 0.17677669529663687f;

  // ---- Phase 1: stage q,k,v fp32 -> bf16 LDS ----
  {
    const size_t base = (size_t)b * NTOK * CEMB;
    #pragma unroll
    for (int m = 0; m < 3; ++m) {
      const float* src = (m == 0 ? qg : m == 1 ? kg : vg) + base;
      char* dst = (m == 0 ? sQ : m == 1 ? sK : sV);
      #pragma unroll
      for (int it = 0; it < 6; ++it) {
        int fi  = it * 512 + tid;
        int row = fi / 48;
        int ce  = (fi - row * 48) * 4;
        const float4 v4 = reinterpret_cast<const float4*>(src)[fi];
        uint2 w;
        w.x = cvtpk(v4.x, v4.y);
        w.y = cvtpk(v4.z, v4.w);
        *reinterpret_cast<uint2*>(dst + row * ROWB + swz(row, ce * 2)) = w;
      }
    }
  }
  __syncthreads();

  // ---- Phase 2: three projection passes (q, k, v) — R8-identical ----
  #pragma unroll
  for (int m = 0; m < 3; ++m) {
    const char* Xs = (m == 0) ? sQ : (m == 1) ? sK : sV;
    const float* bias = (m == 0) ? bq : (m == 1) ? bk : bv;
    f32x4 acc[2][4];
    #pragma unroll
    for (int si = 0; si < 2; ++si) {
      int strip = wave + si * 8;
      if (strip < 12) {
        const u16* Wt = WT + m * 36864 + (strip * 16 + l15) * CEMB + lhi * 8;
        #pragma unroll
        for (int rt = 0; rt < 4; ++rt) { f32x4 z = {0.f,0.f,0.f,0.f}; acc[si][rt] = z; }
        #pragma unroll
        for (int ks = 0; ks < 6; ++ks) {
          bf16x8 bw = *reinterpret_cast<const bf16x8*>(Wt + ks * 32);
          #pragma unroll
          for (int rt = 0; rt < 4; ++rt) {
            int row = rt * 16 + l15;
            bf16x8 ax = *reinterpret_cast<const bf16x8*>(Xs + row * ROWB + swz(row, ks * 64 + lhi * 16));
            acc[si][rt] = __builtin_amdgcn_mfma_f32_16x16x32_bf16(ax, bw, acc[si][rt], 0, 0, 0);
          }
        }
      }
    }
    __syncthreads();   // raw reads of buffer m complete
    #pragma unroll
    for (int si = 0; si < 2; ++si) {
      int strip = wave + si * 8;
      if (strip < 12) {
        int c = strip * 16 + l15;
        float bval = bias[c];
        if (m == 0) {
          #pragma unroll
          for (int rt = 0; rt < 4; ++rt)
            #pragma unroll
            for (int r = 0; r < 4; ++r) {
              int row = rt * 16 + lhi * 4 + r;
              *reinterpret_cast<u16*>(sQ + row * ROWB + swz(row, c * 2)) = f2b((acc[si][rt][r] + bval) * scale);
            }
        } else if (m == 1) {
          #pragma unroll
          for (int rt = 0; rt < 4; ++rt)
            #pragma unroll
            for (int r = 0; r < 4; ++r) {
              int row = rt * 16 + lhi * 4 + r;
              *reinterpret_cast<u16*>(sK + row * ROWB + swz(row, c * 2)) = f2b(acc[si][rt][r] + bval);
            }
        } else {   // vhT[chan c][token], 4 consecutive tokens packed
          #pragma unroll
          for (int rt = 0; rt < 4; ++rt) {
            int t0 = rt * 16 + lhi * 4;
            uint2 w;
            w.x = cvtpk(acc[si][rt][0] + bval, acc[si][rt][1] + bval);
            w.y = cvtpk(acc[si][rt][2] + bval, acc[si][rt][3] + bval);
            *reinterpret_cast<uint2*>(sV + c * VROWB + swz(c, t0 * 2)) = w;
          }
        }
      }
    }
  }
  __syncthreads();   // qh/kh/vhT ready

  // ---- Phase 3: attention; swapped S (lane owns one q-row), R8 PV via bridge ----
  const float* maskw = maskg + (size_t)(b & 1023) * 4096;
  const int rt   = wave & 3;
  const int qrow = rt * 16 + l15;      // this lane's q row
  const int irow = rt * 16 + lhi * 4;  // X-write row base (R8 mapping)

  // hoist mask (head-invariant): lane's 4 consecutive k per ct
  f32x4 mk4[4];
  #pragma unroll
  for (int ct = 0; ct < 4; ++ct)
    mk4[ct] = *reinterpret_cast<const f32x4*>(maskw + qrow * 64 + ct * 16 + lhi * 4);

  #pragma unroll
  for (int ui = 0; ui < 3; ++ui) {
    int u = wave + ui * 8;
    int h = u >> 2;

    f32x4 rb4[4];
    #pragma unroll
    for (int ct = 0; ct < 4; ++ct)
      rb4[ct] = *reinterpret_cast<const f32x4*>(rb + h * 4096 + qrow * 64 + ct * 16 + lhi * 4);

    // S^T = kh @ qh^T: lane gets S[q = qrow][k = ct*16 + lhi*4 + r]
    bf16x8 aq = *reinterpret_cast<const bf16x8*>(sQ + qrow * ROWB + swz(qrow, h * 64 + lhi * 16));
    f32x4 sv[4];
    #pragma unroll
    for (int ct = 0; ct < 4; ++ct) {
      int krow = ct * 16 + l15;
      bf16x8 bkf = *reinterpret_cast<const bf16x8*>(sK + krow * ROWB + swz(krow, h * 64 + lhi * 16));
      f32x4 z = {0.f, 0.f, 0.f, 0.f};
      sv[ct] = __builtin_amdgcn_mfma_f32_16x16x32_bf16(bkf, aq, z, 0, 0, 0);
    }

    float lg[4][4];
    #pragma unroll
    for (int ct = 0; ct < 4; ++ct)
      #pragma unroll
      for (int r = 0; r < 4; ++r)
        lg[ct][r] = sv[ct][r] + rb4[ct][r] + mk4[ct][r];

    // in-register softmax over k: 16 local values, then lanes {l, l^16, l^32, l^48}
    float mx = fmaxf(fmaxf(fmaxf(lg[0][0], lg[0][1]), fmaxf(lg[0][2], lg[0][3])),
                     fmaxf(fmaxf(lg[1][0], lg[1][1]), fmaxf(lg[1][2], lg[1][3])));
    mx = fmaxf(mx, fmaxf(fmaxf(fmaxf(lg[2][0], lg[2][1]), fmaxf(lg[2][2], lg[2][3])),
                         fmaxf(fmaxf(lg[3][0], lg[3][1]), fmaxf(lg[3][2], lg[3][3]))));
    mx = fmaxf(mx, __shfl_xor(mx, 16));
    mx = fmaxf(mx, __shfl_xor(mx, 32));

    float e[4][4];
    float sum = 0.f;
    #pragma unroll
    for (int ct = 0; ct < 4; ++ct)
      #pragma unroll
      for (int r = 0; r < 4; ++r) {
        e[ct][r] = __expf(lg[ct][r] - mx);
        sum += e[ct][r];
      }
    sum += __shfl_xor(sum, 16);
    sum += __shfl_xor(sum, 32);
    float inv = 1.0f / sum;

    float pr[4][4];
    #pragma unroll
    for (int ct = 0; ct < 4; ++ct)
      #pragma unroll
      for (int r = 0; r < 4; ++r)
        pr[ct][r] = e[ct][r] * inv;

    // attn probs: lane's 4 consecutive k at its q-row -> float4 stores
    float* ap = attn_out + ((size_t)b * NH + h) * 4096 + qrow * 64;
    #pragma unroll
    for (int ct = 0; ct < 4; ++ct) {
      f32x4 p4;
      p4[0] = pr[ct][0]; p4[1] = pr[ct][1]; p4[2] = pr[ct][2]; p4[3] = pr[ct][3];
      *reinterpret_cast<f32x4*>(ap + ct * 16 + lhi * 4) = p4;
    }

    // bridge: write pr into R8's sP layout [(kg*16 + q_local)*8 + j] (u16)
    // lane owns q_local = l15, k_local = c*16 + lhi*4 + r -> kg = c*2+(lhi>>1), j = (lhi&1)*4+r
    f32x4 xa[2];
    { f32x4 z = {0.f, 0.f, 0.f, 0.f}; xa[0] = z; xa[1] = z; }
    #pragma unroll
    for (int ks = 0; ks < 2; ++ks) {
      #pragma unroll
      for (int c = 0; c < 2; ++c) {
        int ct = ks * 2 + c;
        int kg = c * 2 + (lhi >> 1);
        uint2 w;
        w.x = cvtpk(pr[ct][0], pr[ct][1]);
        w.y = cvtpk(pr[ct][2], pr[ct][3]);
        *reinterpret_cast<uint2*>(sP + (kg * 16 + l15) * 16 + (lhi & 1) * 8) = w;
      }
      // R8 PV: apf = P[q_local = l15][k_local = lhi*8 + j], conflict-free lane-linear read
      bf16x8 apf = *reinterpret_cast<const bf16x8*>(sP + lane * 16);
      #pragma unroll
      for (int ctv = 0; ctv < 2; ++ctv) {
        int vrow = h * 32 + ctv * 16 + l15;
        bf16x8 bvf = *reinterpret_cast<const bf16x8*>(sV + vrow * VROWB + swz(vrow, ks * 64 + lhi * 16));
        xa[ctv] = __builtin_amdgcn_mfma_f32_16x16x32_bf16(apf, bvf, xa[ctv], 0, 0, 0);
      }
    }

    // X in place over this unit's (rows, head-cols) region of sQ (R8 mapping)
    #pragma unroll
    for (int ctv = 0; ctv < 2; ++ctv)
      #pragma unroll
      for (int r = 0; r < 4; ++r) {
        int xrow = irow + r;
        int xcol = h * 32 + ctv * 16 + l15;
        *reinterpret_cast<u16*>(sQ + xrow * ROWB + swz(xrow, xcol * 2)) = f2b(xa[ctv][r]);
      }
  }
  __syncthreads();   // X complete

  // ---- Phase 4: out = X @ Wp + bp — R8-identical ----
  #pragma unroll
  for (int ui = 0; ui < 3; ++ui) {
    int u2 = wave + ui * 8;
    int ct = u2 % 12;
    int rh = u2 / 12;
    const u16* Wt = WT + 3 * 36864 + (ct * 16 + l15) * CEMB + lhi * 8;
    f32x4 oa[2];
    { f32x4 z = {0.f, 0.f, 0.f, 0.f}; oa[0] = z; oa[1] = z; }
    #pragma unroll
    for (int ks = 0; ks < 6; ++ks) {
      bf16x8 bw = *reinterpret_cast<const bf16x8*>(Wt + ks * 32);
      #pragma unroll
      for (int rr = 0; rr < 2; ++rr) {
        int xrow = rh * 32 + rr * 16 + l15;
        bf16x8 ax = *reinterpret_cast<const bf16x8*>(sQ + xrow * ROWB + swz(xrow, ks * 64 + lhi * 16));
        oa[rr] = __builtin_amdgcn_mfma_f32_16x16x32_bf16(ax, bw, oa[rr], 0, 0, 0);
      }
    }
    float bias = bp[ct * 16 + l15];
    #pragma unroll
    for (int rr = 0; rr < 2; ++rr)
      #pragma unroll
      for (int r = 0; r < 4; ++r)
        xout[((size_t)b * NTOK + rh * 32 + rr * 16 + lhi * 4 + r) * CEMB + ct * 16 + l15] = oa[rr][r] + bias;
  }
}

extern "C" void kernel_launch(void* const* d_in, const int* in_sizes, int n_in,
                              void* d_out, int out_size, void* d_ws, size_t ws_size,
                              hipStream_t stream) {
  const float* q    = (const float*)d_in[0];
  const float* k    = (const float*)d_in[1];
  const float* v    = (const float*)d_in[2];
  const float* mask = (const float*)d_in[3];
  const float* Wq   = (const float*)d_in[4];
  const float* bq   = (const float*)d_in[5];
  const float* Wk   = (const float*)d_in[6];
  const float* bk   = (const float*)d_in[7];
  const float* Wv   = (const float*)d_in[8];
  const float* bv   = (const float*)d_in[9];
  const float* Wp   = (const float*)d_in[10];
  const float* bp   = (const float*)d_in[11];
  const float* btab = (const float*)d_in[12];
  const int*   ridx = (const int*)d_in[13];

  u16*   WT = (u16*)d_ws;                               // 4 * 36864 bf16
  float* rb = (float*)((char*)d_ws + 4 * 36864 * 2);    // 6*64*64 fp32

  float* xout = (float*)d_out;
  float* attn = xout + (size_t)2048 * NTOK * CEMB;

  prep_kernel<<<672, 256, 0, stream>>>(Wq, Wk, Wv, Wp, btab, ridx, WT, rb);
  wattn_kernel<<<2048, 512, 0, stream>>>(q, k, v, mask, bq, bk, bv, bp, WT, rb, xout, attn);
}